// Round 24
// baseline (91.709 us; speedup 1.0000x reference)
//
#include <hip/hip_runtime.h>
#include <hip/hip_bf16.h>
#include <math.h>

// MultiHeadAttention: B=2, S=2048, D=512, H=8, HD=64
constexpr int B_ = 2, S_ = 2048, D_ = 512, H_ = 8, HD_ = 64;
constexpr int M_ = B_ * S_;
constexpr int NT_ = S_ / 64;
constexpr int NSPLIT = 2;
constexpr int NT2 = NT_ / NSPLIT;
constexpr int NTK = NT2 / 2;          // 8 outer iterations of 128 keys (attn)
constexpr int ROWS = B_ * S_ * H_;    // 32768; po half stride = ROWS*64 floats
constexpr int NGROUPS = (B_ * S_ * NT_) / 4;   // 32768 mask int4-groups

typedef short s16x8 __attribute__((ext_vector_type(8)));
typedef float f32x4 __attribute__((ext_vector_type(4)));
typedef unsigned short u16;
typedef unsigned long long u64;

#define SWZ(b) ((b) ^ ((((b) >> 7) & 7) << 4))

constexpr float SCL = 0.18033688f;   // (1/sqrt(64)) * log2(e); folded into Q proj

static __device__ __forceinline__ unsigned int cvt_pk2(float lo, float hi) {
  __hip_bfloat162 h = __float22bfloat162_rn(make_float2(lo, hi));
  return *(unsigned int*)&h;
}
static __device__ __forceinline__ u16 cvt1(float f) {
  __hip_bfloat16 h = __float2bfloat16(f);
  return *(u16*)&h;
}
static __device__ __forceinline__ uint4 pack8(float4 a, float4 b) {
  uint4 r;
  r.x = cvt_pk2(a.x, a.y); r.y = cvt_pk2(a.z, a.w);
  r.z = cvt_pk2(b.x, b.y); r.w = cvt_pk2(b.z, b.w);
  return r;
}
static __device__ __forceinline__ float4 sum_scale(float4 a, float4 b, float s) {
  return make_float4((a.x + b.x) * s, (a.y + b.y) * s,
                     (a.z + b.z) * s, (a.w + b.w) * s);
}

// ---------------------------------------------------------------------------
// Fused QKV projection. R24: 512 threads / 8 waves per block, wave-tile
// 32x32 over the 64x128 output (wm = w&1 row-half, wn = w>>1 col-quarter).
// Same BM=64 x BN=128 tiles, dbuf LDS (48KB), pinned mask prefetch.
// More waves/CU (24 potential vs 12) to cover the staging/barrier stall.
// ---------------------------------------------------------------------------
#define QKV_STEP(BUF, T)                                                      \
  {                                                                           \
    const bool more_ = ((T) < 7);                                             \
    if (more_) {                                                              \
      const int o4 = ((T) + 1) * 16;                                          \
      fx[0] = Xb[o4]; fx[1] = Xb[o4 + 1];                                     \
      fw[0] = Wb[o4]; fw[1] = Wb[o4 + 1]; fw[2] = Wb[o4 + 2]; fw[3] = Wb[o4 + 3]; \
    }                                                                         \
    __builtin_amdgcn_s_setprio(1);                                            \
    _Pragma("unroll")                                                         \
    for (int kw = 0; kw < 2; ++kw) {                                          \
      s16x8 af0 = *(const s16x8*)(shb + SWZ((BUF)*24576 + (wm*32 + l15)*128 + kw*64 + lg*16)); \
      s16x8 af1 = *(const s16x8*)(shb + SWZ((BUF)*24576 + (wm*32 + 16 + l15)*128 + kw*64 + lg*16)); \
      s16x8 bf0 = *(const s16x8*)(shb + SWZ((BUF)*24576 + breg + (brow0)*128 + kw*64 + lg*16)); \
      s16x8 bf1 = *(const s16x8*)(shb + SWZ((BUF)*24576 + breg + (brow0 + 16)*128 + kw*64 + lg*16)); \
      acc[0][0] = __builtin_amdgcn_mfma_f32_16x16x32_bf16(af0, bf0, acc[0][0], 0, 0, 0); \
      acc[0][1] = __builtin_amdgcn_mfma_f32_16x16x32_bf16(af0, bf1, acc[0][1], 0, 0, 0); \
      acc[1][0] = __builtin_amdgcn_mfma_f32_16x16x32_bf16(af1, bf0, acc[1][0], 0, 0, 0); \
      acc[1][1] = __builtin_amdgcn_mfma_f32_16x16x32_bf16(af1, bf1, acc[1][1], 0, 0, 0); \
    }                                                                         \
    __builtin_amdgcn_s_setprio(0);                                            \
    if (more_) {                                                              \
      char* p_ = shb + ((BUF) ^ 1) * 24576;                                   \
      *(uint4*)(p_ + SWZ(xwb)) = pack8(fx[0], fx[1]);                         \
      *(uint4*)(p_ + SWZ(wwb)) = pack8(fw[0], fw[1]);                         \
      *(uint4*)(p_ + SWZ(wwb + 16)) = pack8(fw[2], fw[3]);                    \
    }                                                                         \
    __syncthreads();                                                          \
  }

__global__ __launch_bounds__(512) void gemm_qkv(
    const float* __restrict__ Xq, const float* __restrict__ Wq,
    const float* __restrict__ bq, u16* __restrict__ Yq,
    const float* __restrict__ Xk, const float* __restrict__ Wk,
    const float* __restrict__ bk, u16* __restrict__ Yk,
    const float* __restrict__ Xv, const float* __restrict__ Wv,
    const float* __restrict__ bv, u16* __restrict__ Yv,
    const int* __restrict__ mask, u64* __restrict__ mbits)
{
  const float* X; const float* W; const float* bias; u16* Y;
  const int z = blockIdx.z;
  if (z == 0)      { X = Xq; W = Wq; bias = bq; Y = Yq; }
  else if (z == 1) { X = Xk; W = Wk; bias = bk; Y = Yk; }
  else             { X = Xv; W = Wv; bias = bv; Y = Yv; }

  __shared__ __align__(128) char SH[2][24576];   // [buf][ A 8K | B0 8K | B1 8K ]
  char* shb = &SH[0][0];

  const int tid = threadIdx.x;
  const int lane = tid & 63, w = tid >> 6;       // 8 waves
  const int l15 = lane & 15, lg = lane >> 4;
  const int wm = w & 1, wn = w >> 1;             // 2x4 wave grid, 32x32 tiles
  const int m0 = blockIdx.x * 64, n0 = blockIdx.y * 128;

  // staging maps: X row tr (0..63), 8 floats at (tid&7)*8;
  //               W row wr (0..127), 16 floats at (tid&3)*16.
  const int tr = tid >> 3;
  const int wr = tid >> 2;
  const float4* Xb = (const float4*)&X[(size_t)(m0 + tr) * D_ + (tid & 7) * 8];
  const float4* Wb = (const float4*)&W[(size_t)(n0 + wr) * D_ + (tid & 3) * 16];
  const int xwb = tr * 128 + (tid & 7) * 16;
  const int wwb = 8192 + (wr >> 6) * 8192 + (wr & 63) * 128 + (tid & 3) * 32;
  // B-frag bases for this wave: cols wn*32 + {l15, 16+l15}
  const int breg = 8192 + (wn >> 1) * 8192;      // b0 for wn<2, b1 for wn>=2
  const int brow0 = (wn & 1) * 32 + l15;

  float4 fx[2], fw[4];
  fx[0] = Xb[0]; fx[1] = Xb[1];
#pragma unroll
  for (int i = 0; i < 4; ++i) fw[i] = Wb[i];

  // pinned mask prefetch: 5 unconditional + 1 guarded, stride 6144 waves
  const int bid = blockIdx.x + blockIdx.y * gridDim.x +
                  blockIdx.z * gridDim.x * gridDim.y;     // 0..767
  const int gw = bid * 8 + w;                             // 0..6143
  int4 mv[5];
#pragma unroll
  for (int i = 0; i < 5; ++i)   // g <= 6143 + 4*6144 = 30719 < 32768
    mv[i] = *(const int4*)&mask[(size_t)(gw + i * 6144) * 256 + lane * 4];
  const bool has5 = (gw + 5 * 6144) < NGROUPS;            // gw < 2048
  int4 mv5 = make_int4(0, 0, 0, 0);
  if (has5)
    mv5 = *(const int4*)&mask[(size_t)(gw + 5 * 6144) * 256 + lane * 4];
  __builtin_amdgcn_sched_barrier(0);   // pin: loads issue HERE, results held

  f32x4 acc[2][2];
#pragma unroll
  for (int i = 0; i < 2; ++i)
#pragma unroll
    for (int j = 0; j < 2; ++j) acc[i][j] = (f32x4){0.f, 0.f, 0.f, 0.f};

  {
    char* p = shb;
    *(uint4*)(p + SWZ(xwb)) = pack8(fx[0], fx[1]);
    *(uint4*)(p + SWZ(wwb)) = pack8(fw[0], fw[1]);
    *(uint4*)(p + SWZ(wwb + 16)) = pack8(fw[2], fw[3]);
  }
  __syncthreads();

#pragma unroll 1
  for (int tt = 0; tt < 8; tt += 2) {
    QKV_STEP(0, tt)
    QKV_STEP(1, tt + 1)
  }

  const float oscale = (z == 0) ? SCL : 1.0f;

  if (z != 2) {
    float bias_v[2];
    bias_v[0] = bias[n0 + wn * 32 + l15];
    bias_v[1] = bias[n0 + wn * 32 + 16 + l15];
#pragma unroll
    for (int am = 0; am < 2; ++am)
#pragma unroll
      for (int bn = 0; bn < 2; ++bn)
#pragma unroll
        for (int j = 0; j < 4; ++j) {
          const int row = m0 + wm * 32 + am * 16 + lg * 4 + j;
          const int col = n0 + wn * 32 + bn * 16 + l15;
          Y[(size_t)row * D_ + col] = cvt1((acc[am][bn][j] + bias_v[bn]) * oscale);
        }
  } else {
    // V^T epilogue: two nh-passes; waves with (wn>>1)==nh write their 64x64
    // sub-tile transposed into the A-region scratch, all 512 threads read out.
    const int batch = m0 >> 11, sb = m0 & (S_ - 1);
    float bias_v[2];
    bias_v[0] = bias[n0 + wn * 32 + l15];
    bias_v[1] = bias[n0 + wn * 32 + 16 + l15];
#pragma unroll
    for (int nh = 0; nh < 2; ++nh) {
      const int hh = blockIdx.y * 2 + nh;
      __syncthreads();   // previous pass reads (or K-loop reads) done
      if ((wn >> 1) == nh) {
#pragma unroll
        for (int am = 0; am < 2; ++am)
#pragma unroll
          for (int bn = 0; bn < 2; ++bn) {
            const int dd = (wn & 1) * 32 + bn * 16 + l15;   // d within head
            const int sl = wm * 32 + am * 16 + lg * 4;      // s within tile
            ushort4 pk;
            pk.x = cvt1(acc[am][bn][0] + bias_v[bn]);
            pk.y = cvt1(acc[am][bn][1] + bias_v[bn]);
            pk.z = cvt1(acc[am][bn][2] + bias_v[bn]);
            pk.w = cvt1(acc[am][bn][3] + bias_v[bn]);
            *(ushort4*)(shb + SWZ(dd * 128 + sl * 2)) = pk;
          }
      }
      __syncthreads();
      const int rr = tid >> 3;                 // d row 0..63
      const int rcb = (tid & 7) * 16;          // byte col
      uint4 c0 = *(uint4*)(shb + SWZ(rr * 128 + rcb));
      u16* dst = &Y[(((size_t)batch * H_ + hh) * 64 + rr) * S_ + sb + (tid & 7) * 8];
      *(uint4*)dst = c0;
    }
  }

  // mask pack epilogue: ballots + stores (data already in registers)
#pragma unroll
  for (int i = 0; i < 5; ++i) {
    const int g = gw + i * 6144;
    u64 b0 = __ballot(mv[i].x != 0);
    u64 b1 = __ballot(mv[i].y != 0);
    u64 b2 = __ballot(mv[i].z != 0);
    u64 b3 = __ballot(mv[i].w != 0);
    if (lane < 4) {
      const int q = lane;
      u64 r = ((b0 >> (16 * q)) & 0xFFFFULL)
            | (((b1 >> (16 * q)) & 0xFFFFULL) << 16)
            | (((b2 >> (16 * q)) & 0xFFFFULL) << 32)
            | (((b3 >> (16 * q)) & 0xFFFFULL) << 48);
      mbits[(size_t)g * 4 + q] = r;
    }
  }
  {
    u64 b0 = __ballot(mv5.x != 0);
    u64 b1 = __ballot(mv5.y != 0);
    u64 b2 = __ballot(mv5.z != 0);
    u64 b3 = __ballot(mv5.w != 0);
    if (has5 && lane < 4) {
      const int g = gw + 5 * 6144;
      const int q = lane;
      u64 r = ((b0 >> (16 * q)) & 0xFFFFULL)
            | (((b1 >> (16 * q)) & 0xFFFFULL) << 16)
            | (((b2 >> (16 * q)) & 0xFFFFULL) << 32)
            | (((b3 >> (16 * q)) & 0xFFFFULL) << 48);
      mbits[(size_t)g * 4 + q] = r;
    }
  }
}

// ---------------------------------------------------------------------------
// Out projection with fused split-K combine (R18).
// ---------------------------------------------------------------------------
#define OPROJ_STEP(BUF, T)                                                    \
  {                                                                           \
    const bool more_ = ((T) < 7);                                             \
    if (more_) {                                                              \
      const int t1 = (T) + 1;                                                 \
      const float4* q0 = (const float4*)(poR + t1 * 64);                      \
      const float4* q1 = (const float4*)(poR + 2097152 + t1 * 64);            \
      float4 s0 = q0[0], s1 = q0[1], s2 = q0[2], s3 = q0[3];                  \
      float4 u0 = q1[0], u1 = q1[1], u2 = q1[2], u3 = q1[3];                  \
      const float li = 1.0f / (plR[t1] + plR[ROWS + t1]);                     \
      ax[0] = pack8(sum_scale(s0, u0, li), sum_scale(s1, u1, li));            \
      ax[1] = pack8(sum_scale(s2, u2, li), sum_scale(s3, u3, li));            \
      const int o4 = t1 * 16;                                                 \
      fw[0] = Wb[o4]; fw[1] = Wb[o4 + 1]; fw[2] = Wb[o4 + 2]; fw[3] = Wb[o4 + 3]; \
    }                                                                         \
    __builtin_amdgcn_s_setprio(1);                                            \
    _Pragma("unroll")                                                         \
    for (int kw = 0; kw < 2; ++kw) {                                          \
      s16x8 af0 = *(const s16x8*)(shb + SWZ((BUF)*16384 + (wm*32 + l15)*128 + kw*64 + lg*16)); \
      s16x8 af1 = *(const s16x8*)(shb + SWZ((BUF)*16384 + (wm*32 + 16 + l15)*128 + kw*64 + lg*16)); \
      s16x8 bf0 = *(const s16x8*)(shb + SWZ((BUF)*16384 + 8192 + (wn*32 + l15)*128 + kw*64 + lg*16)); \
      s16x8 bf1 = *(const s16x8*)(shb + SWZ((BUF)*16384 + 8192 + (wn*32 + 16 + l15)*128 + kw*64 + lg*16)); \
      acc[0][0] = __builtin_amdgcn_mfma_f32_16x16x32_bf16(af0, bf0, acc[0][0], 0, 0, 0); \
      acc[0][1] = __builtin_amdgcn_mfma_f32_16x16x32_bf16(af0, bf1, acc[0][1], 0, 0, 0); \
      acc[1][0] = __builtin_amdgcn_mfma_f32_16x16x32_bf16(af1, bf0, acc[1][0], 0, 0, 0); \
      acc[1][1] = __builtin_amdgcn_mfma_f32_16x16x32_bf16(af1, bf1, acc[1][1], 0, 0, 0); \
    }                                                                         \
    __builtin_amdgcn_s_setprio(0);                                            \
    if (more_) {                                                              \
      char* p_ = shb + ((BUF) ^ 1) * 16384;                                   \
      *(uint4*)(p_ + SWZ(awb)) = ax[0];                                       \
      *(uint4*)(p_ + SWZ(awb + 16)) = ax[1];                                  \
      *(uint4*)(p_ + SWZ(bwb)) = pack8(fw[0], fw[1]);                         \
      *(uint4*)(p_ + SWZ(bwb + 16)) = pack8(fw[2], fw[3]);                    \
    }                                                                         \
    __syncthreads();                                                          \
  }

__global__ __launch_bounds__(256) void gemm_oproj(
    const float* __restrict__ po, const float* __restrict__ pl,
    const float* __restrict__ W, const float* __restrict__ bias,
    float* __restrict__ Y)
{
  __shared__ __align__(128) u16 SH[2][2][64][64];
  char* shb = (char*)SH;

  const int tid = threadIdx.x;
  const int lane = tid & 63, w = tid >> 6;
  const int l15 = lane & 15, lg = lane >> 4;
  const int wm = w >> 1, wn = w & 1;
  const int m0 = blockIdx.x * 64, n0 = blockIdx.y * 64;
  const int sr = tid >> 2, sc = (tid & 3) * 16;

  const float* poR = po + (size_t)(m0 + sr) * 512 + sc;
  const float* plR = pl + (size_t)(m0 + sr) * 8;
  const float4* Wb = (const float4*)&W[(size_t)(n0 + sr) * D_ + sc];
  const int awb = sr * 128 + (tid & 3) * 32;
  const int bwb = 8192 + sr * 128 + (tid & 3) * 32;

  f32x4 acc[2][2];
#pragma unroll
  for (int i = 0; i < 2; ++i)
#pragma unroll
    for (int j = 0; j < 2; ++j) acc[i][j] = (f32x4){0.f, 0.f, 0.f, 0.f};

  uint4 ax[2]; float4 fw[4];
  {
    const float4* q0 = (const float4*)(poR);
    const float4* q1 = (const float4*)(poR + 2097152);
    float4 s0 = q0[0], s1 = q0[1], s2 = q0[2], s3 = q0[3];
    float4 u0 = q1[0], u1 = q1[1], u2 = q1[2], u3 = q1[3];
    const float li = 1.0f / (plR[0] + plR[ROWS]);
    ax[0] = pack8(sum_scale(s0, u0, li), sum_scale(s1, u1, li));
    ax[1] = pack8(sum_scale(s2, u2, li), sum_scale(s3, u3, li));
#pragma unroll
    for (int i = 0; i < 4; ++i) fw[i] = Wb[i];
    char* p = shb;
    *(uint4*)(p + SWZ(awb)) = ax[0];
    *(uint4*)(p + SWZ(awb + 16)) = ax[1];
    *(uint4*)(p + SWZ(bwb)) = pack8(fw[0], fw[1]);
    *(uint4*)(p + SWZ(bwb + 16)) = pack8(fw[2], fw[3]);
  }
  __syncthreads();

#pragma unroll 1
  for (int tt = 0; tt < 8; tt += 2) {
    OPROJ_STEP(0, tt)
    OPROJ_STEP(1, tt + 1)
  }

  float bias_v[2];
  bias_v[0] = bias[n0 + wn * 32 + l15];
  bias_v[1] = bias[n0 + wn * 32 + 16 + l15];
#pragma unroll
  for (int am = 0; am < 2; ++am)
#pragma unroll
    for (int bn = 0; bn < 2; ++bn)
#pragma unroll
      for (int j = 0; j < 4; ++j) {
        const int row = m0 + wm * 32 + am * 16 + lg * 4 + j;
        const int col = n0 + wn * 32 + bn * 16 + l15;
        Y[(size_t)row * D_ + col] = acc[am][bn][j] + bias_v[bn];
      }
}

// ---------------------------------------------------------------------------
// Split-K flash attention (R23, passing): dual-chunk interleaved pipeline,
// KVBLK=128 dbuf, no-max softmax, ones-MFMA denominator, permuted mask,
// hoisted swizzled addresses, XCD swizzle.
// ---------------------------------------------------------------------------
__global__ __launch_bounds__(512) void attn_mfma(
    const u16* __restrict__ qp, const u16* __restrict__ kp,
    const u16* __restrict__ vt, const u64* __restrict__ mbits,
    float* __restrict__ po, float* __restrict__ pl)
{
  const int fid = blockIdx.x + 16 * (blockIdx.y + 8 * blockIdx.z);
  const int d = (fid & 7) * 64 + (fid >> 3);
  const int bx = d & 15, by = (d >> 4) & 7, bz = d >> 7;

  const int b = bz >> 1, half = bz & 1;
  const int h = by;
  const int q0 = bx * 128;
  const int kt0 = half * (S_ / NSPLIT);
  const int tid = threadIdx.x;
  const int lane = tid & 63;
  const int w = tid >> 6;
  const int l15 = lane & 15, lg = lane >> 4;

  __shared__ __align__(128) u16 KV[2][2][128][64];   // 64KB
  __shared__ __align__(128) u16 Pl[8][16][64];       // 16KB
  char* kvb = (char*)KV;
  char* plb = (char*)Pl;

  const int qr = q0 + w * 16;

  const u16* qrow = qp + ((size_t)b * S_ + qr + l15) * D_ + h * HD_;
  const s16x8 qf0 = *(const s16x8*)(qrow + lg * 8);
  const s16x8 qf1 = *(const s16x8*)(qrow + 32 + lg * 8);

  s16x8 onesf;
#pragma unroll
  for (int i = 0; i < 8; ++i) onesf[i] = (short)0x3F80;

  f32x4 out[4];
#pragma unroll
  for (int dt = 0; dt < 4; ++dt) out[dt] = (f32x4){0.f, 0.f, 0.f, 0.f};
  float l_s = 0.f;

  const int krow = tid >> 2;
  const int kc = (tid & 3) * 16;
  const int vrow = tid >> 3;
  const int vsel = (tid >> 2) & 1;
  const u16* kbase = kp + (size_t)b * S_ * D_ + h * HD_;
  const u16* vbase = vt + (((size_t)b * H_ + h) * 64 + vrow) * (size_t)S_
                     + kt0 + vsel * 64 + kc;
  const u64* mrow = mbits + ((size_t)b * S_ + qr + l15) * NT_ + half * NT2;

  const int mX = (l15 & 7) << 4;
  const int rd_lo = ((l15 << 7) + lg * 16) ^ mX;
  const int rd_hi = rd_lo ^ 64;
  const int wr_k = ((krow << 7) + (tid & 3) * 32) ^ ((krow & 7) << 4);
  const int wr_v = 16384 + vsel * 8192 +
                   (((vrow << 7) + (tid & 3) * 32) ^ ((vrow & 7) << 4));
  const int pq = w * 2048 + l15 * 128;
  const int pw0 = (pq + lg * 8) ^ mX;
  const int pa_lo = (pq + lg * 16) ^ mX;
  const int pa_hi = pa_lo ^ 64;

  uint4 rk0, rk1, rv0, rv1;
  {
    const u16* ksrc = kbase + (size_t)(kt0 + krow) * D_ + kc;
    rk0 = *(const uint4*)ksrc; rk1 = *(const uint4*)(ksrc + 8);
    rv0 = *(const uint4*)vbase; rv1 = *(const uint4*)(vbase + 8);
    *(uint4*)(kvb + wr_k) = rk0;
    *(uint4*)(kvb + (wr_k ^ 16)) = rk1;
    *(uint4*)(kvb + wr_v) = rv0;
    *(uint4*)(kvb + (wr_v ^ 16)) = rv1;
  }
  u64 msk0 = mrow[0], msk1 = mrow[1];
  __syncthreads();

#pragma unroll 1
  for (int t = 0; t < NTK; ++t) {
    const int cur = t & 1;
    const bool more = (t + 1 < NTK);
    u64 mskn0 = 0, mskn1 = 0;
    if (more) {
      const int kt = (t + 1) * 128;
      const u16* ksrc = kbase + (size_t)(kt0 + kt + krow) * D_ + kc;
      rk0 = *(const uint4*)ksrc; rk1 = *(const uint4*)(ksrc + 8);
      rv0 = *(const uint4*)(vbase + kt); rv1 = *(const uint4*)(vbase + kt + 8);
      mskn0 = mrow[2 * t + 2];
      mskn1 = mrow[2 * t + 3];
    }

    char* rb_lo = kvb + (cur << 15) + rd_lo;
    char* rb_hi = kvb + (cur << 15) + rd_hi;

    f32x4 z0[4], z1[4];
    __builtin_amdgcn_s_setprio(1);
#pragma unroll
    for (int t4 = 0; t4 < 4; ++t4) {
      s16x8 kb0 = *(const s16x8*)(rb_lo + t4 * 2048);
      s16x8 kb1 = *(const s16x8*)(rb_hi + t4 * 2048);
      f32x4 zz = (f32x4){0.f, 0.f, 0.f, 0.f};
      zz = __builtin_amdgcn_mfma_f32_16x16x32_bf16(kb0, qf0, zz, 0, 0, 0);
      zz = __builtin_amdgcn_mfma_f32_16x16x32_bf16(kb1, qf1, zz, 0, 0, 0);
      z0[t4] = zz;
    }
#pragma unroll
    for (int t4 = 0; t4 < 4; ++t4) {
      s16x8 kb0 = *(const s16x8*)(rb_lo + 8192 + t4 * 2048);
      s16x8 kb1 = *(const s16x8*)(rb_hi + 8192 + t4 * 2048);
      f32x4 zz = (f32x4){0.f, 0.f, 0.f, 0.f};
      zz = __builtin_amdgcn_mfma_f32_16x16x32_bf16(kb0, qf0, zz, 0, 0, 0);
      zz = __builtin_amdgcn_mfma_f32_16x16x32_bf16(kb1, qf1, zz, 0, 0, 0);
      z1[t4] = zz;
    }
    __builtin_amdgcn_s_setprio(0);

    {
      const unsigned mlo = (unsigned)(msk0 >> lg);
      const unsigned mhi = (unsigned)(msk0 >> (lg + 32));
      float x[4][4];
#pragma unroll
      for (int t4 = 0; t4 < 4; ++t4)
#pragma unroll
        for (int r = 0; r < 4; ++r) {
          const unsigned bit = (r < 2) ? ((mlo >> (16 * r + 4 * t4)) & 1u)
                                       : ((mhi >> (16 * (r - 2) + 4 * t4)) & 1u);
          x[t4][r] = exp2f(bit ? z0[t4][r] : -1.0e9f);
        }
#pragma unroll
      for (int t4 = 0; t4 < 4; ++t4) {
        uint2 pk;
        pk.x = cvt_pk2(x[t4][0], x[t4][1]);
        pk.y = cvt_pk2(x[t4][2], x[t4][3]);
        *(uint2*)(plb + (pw0 ^ (t4 * 32))) = pk;
      }
    }
    s16x8 p00 = *(const s16x8*)(plb + pa_lo);
    s16x8 p01 = *(const s16x8*)(plb + pa_hi);

    {
      const unsigned mlo = (unsigned)(msk1 >> lg);
      const unsigned mhi = (unsigned)(msk1 >> (lg + 32));
      float x[4][4];
#pragma unroll
      for (int t4 = 0; t4 < 4; ++t4)
#pragma unroll
        for (int r = 0; r < 4; ++r) {
          const unsigned bit = (r < 2) ? ((mlo >> (16 * r + 4 * t4)) & 1u)
                                       : ((mhi >> (16 * (r - 2) + 4 * t4)) & 1u);
          x[t4][r] = exp2f(bit ? z1[t4][r] : -1.0e9f);
        }
#pragma unroll
      for (int t4 = 0; t4 < 4; ++t4) {
        uint2 pk;
        pk.x = cvt_pk2(x[t4][0], x[t4][1]);
        pk.y = cvt_pk2(x[t4][2], x[t4][3]);
        *(uint2*)(plb + (pw0 ^ (t4 * 32))) = pk;
      }
    }
    s16x8 p10 = *(const s16x8*)(plb + pa_lo);
    s16x8 p11 = *(const s16x8*)(plb + pa_hi);

    __builtin_amdgcn_s_setprio(1);
    f32x4 zl0 = (f32x4){0.f, 0.f, 0.f, 0.f};
    zl0 = __builtin_amdgcn_mfma_f32_16x16x32_bf16(onesf, p00, zl0, 0, 0, 0);
    zl0 = __builtin_amdgcn_mfma_f32_16x16x32_bf16(onesf, p01, zl0, 0, 0, 0);
#pragma unroll
    for (int dt = 0; dt < 4; ++dt) {
      s16x8 va0 = *(const s16x8*)(rb_lo + 16384 + dt * 2048);
      s16x8 va1 = *(const s16x8*)(rb_hi + 16384 + dt * 2048);
      out[dt] = __builtin_amdgcn_mfma_f32_16x16x32_bf16(va0, p00, out[dt], 0, 0, 0);
      out[dt] = __builtin_amdgcn_mfma_f32_16x16x32_bf16(va1, p01, out[dt], 0, 0, 0);
    }
    f32x4 zl1 = (f32x4){0.f, 0.f, 0.f, 0.f};
    zl1 = __builtin_amdgcn_mfma_f32_16x16x32_bf16(onesf, p10, zl1, 0, 0, 0);
    zl1 = __builtin_amdgcn_mfma_f32_16x16x32_bf16(onesf, p11, zl1, 0, 0, 0);
#pragma unroll
    for (int dt = 0; dt < 4; ++dt) {
      s16x8 va0 = *(const s16x8*)(rb_lo + 24576 + dt * 2048);
      s16x8 va1 = *(const s16x8*)(rb_hi + 24576 + dt * 2048);
      out[dt] = __builtin_amdgcn_mfma_f32_16x16x32_bf16(va0, p10, out[dt], 0, 0, 0);
      out[dt] = __builtin_amdgcn_mfma_f32_16x16x32_bf16(va1, p11, out[dt], 0, 0, 0);
    }
    __builtin_amdgcn_s_setprio(0);
    l_s += zl0[0] + zl1[0];

    if (more) {
      char* wb = kvb + ((cur ^ 1) << 15);
      *(uint4*)(wb + wr_k) = rk0;
      *(uint4*)(wb + (wr_k ^ 16)) = rk1;
      *(uint4*)(wb + wr_v) = rv0;
      *(uint4*)(wb + (wr_v ^ 16)) = rv1;
      msk0 = mskn0; msk1 = mskn1;
    }
    __syncthreads();
  }

  const int rowi = ((b * S_ + qr + l15) * H_) + h;
  float* pobase = po + ((size_t)half * ROWS + rowi) * 64;
#pragma unroll
  for (int dt = 0; dt < 4; ++dt) {
    float4 o = make_float4(out[dt][0], out[dt][1], out[dt][2], out[dt][3]);
    *(float4*)&pobase[dt * 16 + lg * 4] = o;
  }
  if (lg == 0) pl[(size_t)half * ROWS + rowi] = l_s;
}

// ---------------------------------------------------------------------------
extern "C" void kernel_launch(void* const* d_in, const int* in_sizes, int n_in,
                              void* d_out, int out_size, void* d_ws,
                              size_t ws_size, hipStream_t stream)
{
  const float* q_in = (const float*)d_in[0];
  const float* k_in = (const float*)d_in[1];
  const float* v_in = (const float*)d_in[2];
  const int*   mask = (const int*)d_in[3];
  const float* W1 = (const float*)d_in[4];
  const float* b1 = (const float*)d_in[5];
  const float* W2 = (const float*)d_in[6];
  const float* b2 = (const float*)d_in[7];
  const float* W3 = (const float*)d_in[8];
  const float* b3 = (const float*)d_in[9];
  const float* Wo = (const float*)d_in[10];
  const float* bo = (const float*)d_in[11];
  float* out = (float*)d_out;

  char* ws = (char*)d_ws;
  u16* qp = (u16*)ws;
  u16* kp = (u16*)(ws + (4u << 20));
  u16* vtp = (u16*)(ws + (8u << 20));
  u64* mbits = (u64*)(ws + (12u << 20));
  float* pl = (float*)(ws + (13u << 20));
  float* po = (float*)(ws + (13u << 20) + (512u << 10));

  gemm_qkv<<<dim3(M_ / 64, D_ / 128, 3), dim3(512), 0, stream>>>(
      q_in, W1, b1, qp, k_in, W2, b2, kp, v_in, W3, b3, vtp, mask, mbits);
  attn_mfma<<<dim3(S_ / 128, H_, B_ * NSPLIT), dim3(512), 0, stream>>>(
      qp, kp, vtp, mbits, po, pl);
  gemm_oproj<<<dim3(M_ / 64, D_ / 64), dim3(256), 0, stream>>>(po, pl, Wo, bo, out);
}

// Round 25
// 88.339 us; speedup vs baseline: 1.0381x; 1.0381x over previous
//
#include <hip/hip_runtime.h>
#include <hip/hip_bf16.h>
#include <math.h>

// MultiHeadAttention: B=2, S=2048, D=512, H=8, HD=64
constexpr int B_ = 2, S_ = 2048, D_ = 512, H_ = 8, HD_ = 64;
constexpr int M_ = B_ * S_;
constexpr int NT_ = S_ / 64;
constexpr int NSPLIT = 2;
constexpr int NT2 = NT_ / NSPLIT;
constexpr int NTK = NT2 / 2;          // 8 outer iterations of 128 keys
constexpr int ROWS = B_ * S_ * H_;    // 32768; po half stride = ROWS*64 floats
constexpr int NGROUPS = (B_ * S_ * NT_) / 4;   // 32768 mask int4-groups

typedef short s16x8 __attribute__((ext_vector_type(8)));
typedef float f32x4 __attribute__((ext_vector_type(4)));
typedef unsigned short u16;
typedef unsigned long long u64;

#define SWZ(b) ((b) ^ ((((b) >> 7) & 7) << 4))

constexpr float SCL = 0.18033688f;   // (1/sqrt(64)) * log2(e); folded into Q proj

static __device__ __forceinline__ unsigned int cvt_pk2(float lo, float hi) {
  __hip_bfloat162 h = __float22bfloat162_rn(make_float2(lo, hi));
  return *(unsigned int*)&h;
}
static __device__ __forceinline__ u16 cvt1(float f) {
  __hip_bfloat16 h = __float2bfloat16(f);
  return *(u16*)&h;
}
static __device__ __forceinline__ uint4 pack8(float4 a, float4 b) {
  uint4 r;
  r.x = cvt_pk2(a.x, a.y); r.y = cvt_pk2(a.z, a.w);
  r.z = cvt_pk2(b.x, b.y); r.w = cvt_pk2(b.z, b.w);
  return r;
}
static __device__ __forceinline__ float4 sum_scale(float4 a, float4 b, float s) {
  return make_float4((a.x + b.x) * s, (a.y + b.y) * s,
                     (a.z + b.z) * s, (a.w + b.w) * s);
}

// ---------------------------------------------------------------------------
// Fused QKV projection (BM=64 x BN=128) + pinned mask prefetch (R20).
// ---------------------------------------------------------------------------
#define QKV_STEP(BUF, T)                                                      \
  {                                                                           \
    const bool more_ = ((T) < 7);                                             \
    if (more_) {                                                              \
      const int o4 = ((T) + 1) * 16;                                          \
      fx[0] = Xb[o4];  fx[1] = Xb[o4 + 1];  fx[2] = Xb[o4 + 2];  fx[3] = Xb[o4 + 3]; \
      fw0[0] = W0b[o4]; fw0[1] = W0b[o4 + 1]; fw0[2] = W0b[o4 + 2]; fw0[3] = W0b[o4 + 3]; \
      fw1[0] = W1b[o4]; fw1[1] = W1b[o4 + 1]; fw1[2] = W1b[o4 + 2]; fw1[3] = W1b[o4 + 3]; \
    }                                                                         \
    __builtin_amdgcn_s_setprio(1);                                            \
    _Pragma("unroll")                                                         \
    for (int kw = 0; kw < 2; ++kw) {                                          \
      s16x8 af0 = *(const s16x8*)(shb + SWZ((BUF)*24576 + (wm*32 + l15)*128 + kw*64 + lg*16)); \
      s16x8 af1 = *(const s16x8*)(shb + SWZ((BUF)*24576 + (wm*32 + 16 + l15)*128 + kw*64 + lg*16)); \
      s16x8 b00 = *(const s16x8*)(shb + SWZ((BUF)*24576 + 8192 + (wn*32 + l15)*128 + kw*64 + lg*16)); \
      s16x8 b01 = *(const s16x8*)(shb + SWZ((BUF)*24576 + 8192 + (wn*32 + 16 + l15)*128 + kw*64 + lg*16)); \
      s16x8 b10 = *(const s16x8*)(shb + SWZ((BUF)*24576 + 16384 + (wn*32 + l15)*128 + kw*64 + lg*16)); \
      s16x8 b11 = *(const s16x8*)(shb + SWZ((BUF)*24576 + 16384 + (wn*32 + 16 + l15)*128 + kw*64 + lg*16)); \
      acc[0][0][0] = __builtin_amdgcn_mfma_f32_16x16x32_bf16(af0, b00, acc[0][0][0], 0, 0, 0); \
      acc[0][0][1] = __builtin_amdgcn_mfma_f32_16x16x32_bf16(af0, b01, acc[0][0][1], 0, 0, 0); \
      acc[0][1][0] = __builtin_amdgcn_mfma_f32_16x16x32_bf16(af1, b00, acc[0][1][0], 0, 0, 0); \
      acc[0][1][1] = __builtin_amdgcn_mfma_f32_16x16x32_bf16(af1, b01, acc[0][1][1], 0, 0, 0); \
      acc[1][0][0] = __builtin_amdgcn_mfma_f32_16x16x32_bf16(af0, b10, acc[1][0][0], 0, 0, 0); \
      acc[1][0][1] = __builtin_amdgcn_mfma_f32_16x16x32_bf16(af0, b11, acc[1][0][1], 0, 0, 0); \
      acc[1][1][0] = __builtin_amdgcn_mfma_f32_16x16x32_bf16(af1, b10, acc[1][1][0], 0, 0, 0); \
      acc[1][1][1] = __builtin_amdgcn_mfma_f32_16x16x32_bf16(af1, b11, acc[1][1][1], 0, 0, 0); \
    }                                                                         \
    __builtin_amdgcn_s_setprio(0);                                            \
    if (more_) {                                                              \
      char* p_ = shb + ((BUF) ^ 1) * 24576;                                   \
      *(uint4*)(p_ + SWZ(awb)) = pack8(fx[0], fx[1]);                         \
      *(uint4*)(p_ + SWZ(awb + 16)) = pack8(fx[2], fx[3]);                    \
      *(uint4*)(p_ + SWZ(b0wb)) = pack8(fw0[0], fw0[1]);                      \
      *(uint4*)(p_ + SWZ(b0wb + 16)) = pack8(fw0[2], fw0[3]);                 \
      *(uint4*)(p_ + SWZ(b1wb)) = pack8(fw1[0], fw1[1]);                      \
      *(uint4*)(p_ + SWZ(b1wb + 16)) = pack8(fw1[2], fw1[3]);                 \
    }                                                                         \
    __syncthreads();                                                          \
  }

__global__ __launch_bounds__(256) void gemm_qkv(
    const float* __restrict__ Xq, const float* __restrict__ Wq,
    const float* __restrict__ bq, u16* __restrict__ Yq,
    const float* __restrict__ Xk, const float* __restrict__ Wk,
    const float* __restrict__ bk, u16* __restrict__ Yk,
    const float* __restrict__ Xv, const float* __restrict__ Wv,
    const float* __restrict__ bv, u16* __restrict__ Yv,
    const int* __restrict__ mask, u64* __restrict__ mbits)
{
  const float* X; const float* W; const float* bias; u16* Y;
  const int z = blockIdx.z;
  if (z == 0)      { X = Xq; W = Wq; bias = bq; Y = Yq; }
  else if (z == 1) { X = Xk; W = Wk; bias = bk; Y = Yk; }
  else             { X = Xv; W = Wv; bias = bv; Y = Yv; }

  __shared__ __align__(128) char SH[2][24576];
  char* shb = &SH[0][0];

  const int tid = threadIdx.x;
  const int lane = tid & 63, w = tid >> 6;
  const int l15 = lane & 15, lg = lane >> 4;
  const int wm = w >> 1, wn = w & 1;
  const int m0 = blockIdx.x * 64, n0 = blockIdx.y * 128;
  const int sr = tid >> 2, sc = (tid & 3) * 16;

  const float4* Xb  = (const float4*)&X[(size_t)(m0 + sr) * D_ + sc];
  const float4* W0b = (const float4*)&W[(size_t)(n0 + sr) * D_ + sc];
  const float4* W1b = (const float4*)&W[(size_t)(n0 + 64 + sr) * D_ + sc];
  const int awb  = sr * 128 + (tid & 3) * 32;
  const int b0wb = 8192 + awb;
  const int b1wb = 16384 + awb;

  float4 fx[4], fw0[4], fw1[4];
#pragma unroll
  for (int i = 0; i < 4; ++i) { fx[i] = Xb[i]; fw0[i] = W0b[i]; fw1[i] = W1b[i]; }

  const int bid = blockIdx.x + blockIdx.y * gridDim.x +
                  blockIdx.z * gridDim.x * gridDim.y;     // 0..767
  const int gw = bid * 4 + w;                             // 0..3071
  int4 mv[10];
#pragma unroll
  for (int i = 0; i < 10; ++i)
    mv[i] = *(const int4*)&mask[(size_t)(gw + i * 3072) * 256 + lane * 4];
  const bool has10 = (gw + 10 * 3072) < NGROUPS;
  int4 mv10 = make_int4(0, 0, 0, 0);
  if (has10)
    mv10 = *(const int4*)&mask[(size_t)(gw + 10 * 3072) * 256 + lane * 4];
  __builtin_amdgcn_sched_barrier(0);

  f32x4 acc[2][2][2];
#pragma unroll
  for (int nh = 0; nh < 2; ++nh)
#pragma unroll
    for (int i = 0; i < 2; ++i)
#pragma unroll
      for (int j = 0; j < 2; ++j) acc[nh][i][j] = (f32x4){0.f, 0.f, 0.f, 0.f};

  {
    char* p = shb;
    *(uint4*)(p + SWZ(awb)) = pack8(fx[0], fx[1]);
    *(uint4*)(p + SWZ(awb + 16)) = pack8(fx[2], fx[3]);
    *(uint4*)(p + SWZ(b0wb)) = pack8(fw0[0], fw0[1]);
    *(uint4*)(p + SWZ(b0wb + 16)) = pack8(fw0[2], fw0[3]);
    *(uint4*)(p + SWZ(b1wb)) = pack8(fw1[0], fw1[1]);
    *(uint4*)(p + SWZ(b1wb + 16)) = pack8(fw1[2], fw1[3]);
  }
  __syncthreads();

#pragma unroll 1
  for (int tt = 0; tt < 8; tt += 2) {
    QKV_STEP(0, tt)
    QKV_STEP(1, tt + 1)
  }

  const float oscale = (z == 0) ? SCL : 1.0f;

  if (z != 2) {
#pragma unroll
    for (int nh = 0; nh < 2; ++nh) {
      float bias_v[2];
      bias_v[0] = bias[n0 + nh * 64 + wn * 32 + l15];
      bias_v[1] = bias[n0 + nh * 64 + wn * 32 + 16 + l15];
#pragma unroll
      for (int am = 0; am < 2; ++am)
#pragma unroll
        for (int bn = 0; bn < 2; ++bn)
#pragma unroll
          for (int j = 0; j < 4; ++j) {
            const int row = m0 + wm * 32 + am * 16 + lg * 4 + j;
            const int col = n0 + nh * 64 + wn * 32 + bn * 16 + l15;
            Y[(size_t)row * D_ + col] = cvt1((acc[nh][am][bn][j] + bias_v[bn]) * oscale);
          }
    }
  } else {
    const int batch = m0 >> 11, sb = m0 & (S_ - 1);
#pragma unroll
    for (int nh = 0; nh < 2; ++nh) {
      const int hh = blockIdx.y * 2 + nh;
      float bias_v[2];
      bias_v[0] = bias[n0 + nh * 64 + wn * 32 + l15];
      bias_v[1] = bias[n0 + nh * 64 + wn * 32 + 16 + l15];
      __syncthreads();
#pragma unroll
      for (int am = 0; am < 2; ++am)
#pragma unroll
        for (int bn = 0; bn < 2; ++bn) {
          const int dd = wn * 32 + bn * 16 + l15;
          const int sl = wm * 32 + am * 16 + lg * 4;
          ushort4 pk;
          pk.x = cvt1(acc[nh][am][bn][0] + bias_v[bn]);
          pk.y = cvt1(acc[nh][am][bn][1] + bias_v[bn]);
          pk.z = cvt1(acc[nh][am][bn][2] + bias_v[bn]);
          pk.w = cvt1(acc[nh][am][bn][3] + bias_v[bn]);
          *(ushort4*)(shb + SWZ(dd * 128 + sl * 2)) = pk;
        }
      __syncthreads();
      const int cr = sr * 128 + (tid & 3) * 32;
      uint4 c0 = *(uint4*)(shb + SWZ(cr));
      uint4 c1 = *(uint4*)(shb + SWZ(cr + 16));
      u16* dst = &Y[(((size_t)batch * H_ + hh) * 64 + sr) * S_ + sb + sc];
      *(uint4*)dst = c0;
      *(uint4*)(dst + 8) = c1;
    }
  }

#pragma unroll
  for (int i = 0; i < 10; ++i) {
    const int g = gw + i * 3072;
    u64 b0 = __ballot(mv[i].x != 0);
    u64 b1 = __ballot(mv[i].y != 0);
    u64 b2 = __ballot(mv[i].z != 0);
    u64 b3 = __ballot(mv[i].w != 0);
    if (lane < 4) {
      const int q = lane;
      u64 r = ((b0 >> (16 * q)) & 0xFFFFULL)
            | (((b1 >> (16 * q)) & 0xFFFFULL) << 16)
            | (((b2 >> (16 * q)) & 0xFFFFULL) << 32)
            | (((b3 >> (16 * q)) & 0xFFFFULL) << 48);
      mbits[(size_t)g * 4 + q] = r;
    }
  }
  {
    u64 b0 = __ballot(mv10.x != 0);
    u64 b1 = __ballot(mv10.y != 0);
    u64 b2 = __ballot(mv10.z != 0);
    u64 b3 = __ballot(mv10.w != 0);
    if (has10 && lane < 4) {
      const int g = gw + 10 * 3072;
      const int q = lane;
      u64 r = ((b0 >> (16 * q)) & 0xFFFFULL)
            | (((b1 >> (16 * q)) & 0xFFFFULL) << 16)
            | (((b2 >> (16 * q)) & 0xFFFFULL) << 32)
            | (((b3 >> (16 * q)) & 0xFFFFULL) << 48);
      mbits[(size_t)g * 4 + q] = r;
    }
  }
}

// ---------------------------------------------------------------------------
// Out projection with fused split-K combine (R18).
// ---------------------------------------------------------------------------
#define OPROJ_STEP(BUF, T)                                                    \
  {                                                                           \
    const bool more_ = ((T) < 7);                                             \
    if (more_) {                                                              \
      const int t1 = (T) + 1;                                                 \
      const float4* q0 = (const float4*)(poR + t1 * 64);                      \
      const float4* q1 = (const float4*)(poR + 2097152 + t1 * 64);            \
      float4 s0 = q0[0], s1 = q0[1], s2 = q0[2], s3 = q0[3];                  \
      float4 u0 = q1[0], u1 = q1[1], u2 = q1[2], u3 = q1[3];                  \
      const float li = 1.0f / (plR[t1] + plR[ROWS + t1]);                     \
      ax[0] = pack8(sum_scale(s0, u0, li), sum_scale(s1, u1, li));            \
      ax[1] = pack8(sum_scale(s2, u2, li), sum_scale(s3, u3, li));            \
      const int o4 = t1 * 16;                                                 \
      fw[0] = Wb[o4]; fw[1] = Wb[o4 + 1]; fw[2] = Wb[o4 + 2]; fw[3] = Wb[o4 + 3]; \
    }                                                                         \
    __builtin_amdgcn_s_setprio(1);                                            \
    _Pragma("unroll")                                                         \
    for (int kw = 0; kw < 2; ++kw) {                                          \
      s16x8 af0 = *(const s16x8*)(shb + SWZ((BUF)*16384 + (wm*32 + l15)*128 + kw*64 + lg*16)); \
      s16x8 af1 = *(const s16x8*)(shb + SWZ((BUF)*16384 + (wm*32 + 16 + l15)*128 + kw*64 + lg*16)); \
      s16x8 bf0 = *(const s16x8*)(shb + SWZ((BUF)*16384 + 8192 + (wn*32 + l15)*128 + kw*64 + lg*16)); \
      s16x8 bf1 = *(const s16x8*)(shb + SWZ((BUF)*16384 + 8192 + (wn*32 + 16 + l15)*128 + kw*64 + lg*16)); \
      acc[0][0] = __builtin_amdgcn_mfma_f32_16x16x32_bf16(af0, bf0, acc[0][0], 0, 0, 0); \
      acc[0][1] = __builtin_amdgcn_mfma_f32_16x16x32_bf16(af0, bf1, acc[0][1], 0, 0, 0); \
      acc[1][0] = __builtin_amdgcn_mfma_f32_16x16x32_bf16(af1, bf0, acc[1][0], 0, 0, 0); \
      acc[1][1] = __builtin_amdgcn_mfma_f32_16x16x32_bf16(af1, bf1, acc[1][1], 0, 0, 0); \
    }                                                                         \
    __builtin_amdgcn_s_setprio(0);                                            \
    if (more_) {                                                              \
      char* p_ = shb + ((BUF) ^ 1) * 16384;                                   \
      *(uint4*)(p_ + SWZ(awb)) = ax[0];                                       \
      *(uint4*)(p_ + SWZ(awb + 16)) = ax[1];                                  \
      *(uint4*)(p_ + SWZ(bwb)) = pack8(fw[0], fw[1]);                         \
      *(uint4*)(p_ + SWZ(bwb + 16)) = pack8(fw[2], fw[3]);                    \
    }                                                                         \
    __syncthreads();                                                          \
  }

__global__ __launch_bounds__(256) void gemm_oproj(
    const float* __restrict__ po, const float* __restrict__ pl,
    const float* __restrict__ W, const float* __restrict__ bias,
    float* __restrict__ Y)
{
  __shared__ __align__(128) u16 SH[2][2][64][64];
  char* shb = (char*)SH;

  const int tid = threadIdx.x;
  const int lane = tid & 63, w = tid >> 6;
  const int l15 = lane & 15, lg = lane >> 4;
  const int wm = w >> 1, wn = w & 1;
  const int m0 = blockIdx.x * 64, n0 = blockIdx.y * 64;
  const int sr = tid >> 2, sc = (tid & 3) * 16;

  const float* poR = po + (size_t)(m0 + sr) * 512 + sc;
  const float* plR = pl + (size_t)(m0 + sr) * 8;
  const float4* Wb = (const float4*)&W[(size_t)(n0 + sr) * D_ + sc];
  const int awb = sr * 128 + (tid & 3) * 32;
  const int bwb = 8192 + sr * 128 + (tid & 3) * 32;

  f32x4 acc[2][2];
#pragma unroll
  for (int i = 0; i < 2; ++i)
#pragma unroll
    for (int j = 0; j < 2; ++j) acc[i][j] = (f32x4){0.f, 0.f, 0.f, 0.f};

  uint4 ax[2]; float4 fw[4];
  {
    const float4* q0 = (const float4*)(poR);
    const float4* q1 = (const float4*)(poR + 2097152);
    float4 s0 = q0[0], s1 = q0[1], s2 = q0[2], s3 = q0[3];
    float4 u0 = q1[0], u1 = q1[1], u2 = q1[2], u3 = q1[3];
    const float li = 1.0f / (plR[0] + plR[ROWS]);
    ax[0] = pack8(sum_scale(s0, u0, li), sum_scale(s1, u1, li));
    ax[1] = pack8(sum_scale(s2, u2, li), sum_scale(s3, u3, li));
#pragma unroll
    for (int i = 0; i < 4; ++i) fw[i] = Wb[i];
    char* p = shb;
    *(uint4*)(p + SWZ(awb)) = ax[0];
    *(uint4*)(p + SWZ(awb + 16)) = ax[1];
    *(uint4*)(p + SWZ(bwb)) = pack8(fw[0], fw[1]);
    *(uint4*)(p + SWZ(bwb + 16)) = pack8(fw[2], fw[3]);
  }
  __syncthreads();

#pragma unroll 1
  for (int tt = 0; tt < 8; tt += 2) {
    OPROJ_STEP(0, tt)
    OPROJ_STEP(1, tt + 1)
  }

  float bias_v[2];
  bias_v[0] = bias[n0 + wn * 32 + l15];
  bias_v[1] = bias[n0 + wn * 32 + 16 + l15];
#pragma unroll
  for (int am = 0; am < 2; ++am)
#pragma unroll
    for (int bn = 0; bn < 2; ++bn)
#pragma unroll
      for (int j = 0; j < 4; ++j) {
        const int row = m0 + wm * 32 + am * 16 + lg * 4 + j;
        const int col = n0 + wn * 32 + bn * 16 + l15;
        Y[(size_t)row * D_ + col] = acc[am][bn][j] + bias_v[bn];
      }
}

// ---------------------------------------------------------------------------
// Split-K flash attention (R23 best): dual-chunk interleaved pipeline,
// KVBLK=128 dbuf, no-max softmax, ones-MFMA denominator, permuted mask,
// hoisted swizzled addresses, XCD swizzle.
// ---------------------------------------------------------------------------
__global__ __launch_bounds__(512) void attn_mfma(
    const u16* __restrict__ qp, const u16* __restrict__ kp,
    const u16* __restrict__ vt, const u64* __restrict__ mbits,
    float* __restrict__ po, float* __restrict__ pl)
{
  const int fid = blockIdx.x + 16 * (blockIdx.y + 8 * blockIdx.z);
  const int d = (fid & 7) * 64 + (fid >> 3);
  const int bx = d & 15, by = (d >> 4) & 7, bz = d >> 7;

  const int b = bz >> 1, half = bz & 1;
  const int h = by;
  const int q0 = bx * 128;
  const int kt0 = half * (S_ / NSPLIT);
  const int tid = threadIdx.x;
  const int lane = tid & 63;
  const int w = tid >> 6;
  const int l15 = lane & 15, lg = lane >> 4;

  __shared__ __align__(128) u16 KV[2][2][128][64];   // 64KB
  __shared__ __align__(128) u16 Pl[8][16][64];       // 16KB
  char* kvb = (char*)KV;
  char* plb = (char*)Pl;

  const int qr = q0 + w * 16;

  const u16* qrow = qp + ((size_t)b * S_ + qr + l15) * D_ + h * HD_;
  const s16x8 qf0 = *(const s16x8*)(qrow + lg * 8);
  const s16x8 qf1 = *(const s16x8*)(qrow + 32 + lg * 8);

  s16x8 onesf;
#pragma unroll
  for (int i = 0; i < 8; ++i) onesf[i] = (short)0x3F80;

  f32x4 out[4];
#pragma unroll
  for (int dt = 0; dt < 4; ++dt) out[dt] = (f32x4){0.f, 0.f, 0.f, 0.f};
  float l_s = 0.f;

  const int krow = tid >> 2;
  const int kc = (tid & 3) * 16;
  const int vrow = tid >> 3;
  const int vsel = (tid >> 2) & 1;
  const u16* kbase = kp + (size_t)b * S_ * D_ + h * HD_;
  const u16* vbase = vt + (((size_t)b * H_ + h) * 64 + vrow) * (size_t)S_
                     + kt0 + vsel * 64 + kc;
  const u64* mrow = mbits + ((size_t)b * S_ + qr + l15) * NT_ + half * NT2;

  const int mX = (l15 & 7) << 4;
  const int rd_lo = ((l15 << 7) + lg * 16) ^ mX;
  const int rd_hi = rd_lo ^ 64;
  const int wr_k = ((krow << 7) + (tid & 3) * 32) ^ ((krow & 7) << 4);
  const int wr_v = 16384 + vsel * 8192 +
                   (((vrow << 7) + (tid & 3) * 32) ^ ((vrow & 7) << 4));
  const int pq = w * 2048 + l15 * 128;
  const int pw0 = (pq + lg * 8) ^ mX;
  const int pa_lo = (pq + lg * 16) ^ mX;
  const int pa_hi = pa_lo ^ 64;

  uint4 rk0, rk1, rv0, rv1;
  {
    const u16* ksrc = kbase + (size_t)(kt0 + krow) * D_ + kc;
    rk0 = *(const uint4*)ksrc; rk1 = *(const uint4*)(ksrc + 8);
    rv0 = *(const uint4*)vbase; rv1 = *(const uint4*)(vbase + 8);
    *(uint4*)(kvb + wr_k) = rk0;
    *(uint4*)(kvb + (wr_k ^ 16)) = rk1;
    *(uint4*)(kvb + wr_v) = rv0;
    *(uint4*)(kvb + (wr_v ^ 16)) = rv1;
  }
  u64 msk0 = mrow[0], msk1 = mrow[1];
  __syncthreads();

#pragma unroll 1
  for (int t = 0; t < NTK; ++t) {
    const int cur = t & 1;
    const bool more = (t + 1 < NTK);
    u64 mskn0 = 0, mskn1 = 0;
    if (more) {
      const int kt = (t + 1) * 128;
      const u16* ksrc = kbase + (size_t)(kt0 + kt + krow) * D_ + kc;
      rk0 = *(const uint4*)ksrc; rk1 = *(const uint4*)(ksrc + 8);
      rv0 = *(const uint4*)(vbase + kt); rv1 = *(const uint4*)(vbase + kt + 8);
      mskn0 = mrow[2 * t + 2];
      mskn1 = mrow[2 * t + 3];
    }

    char* rb_lo = kvb + (cur << 15) + rd_lo;
    char* rb_hi = kvb + (cur << 15) + rd_hi;

    f32x4 z0[4], z1[4];
    __builtin_amdgcn_s_setprio(1);
#pragma unroll
    for (int t4 = 0; t4 < 4; ++t4) {
      s16x8 kb0 = *(const s16x8*)(rb_lo + t4 * 2048);
      s16x8 kb1 = *(const s16x8*)(rb_hi + t4 * 2048);
      f32x4 zz = (f32x4){0.f, 0.f, 0.f, 0.f};
      zz = __builtin_amdgcn_mfma_f32_16x16x32_bf16(kb0, qf0, zz, 0, 0, 0);
      zz = __builtin_amdgcn_mfma_f32_16x16x32_bf16(kb1, qf1, zz, 0, 0, 0);
      z0[t4] = zz;
    }
#pragma unroll
    for (int t4 = 0; t4 < 4; ++t4) {
      s16x8 kb0 = *(const s16x8*)(rb_lo + 8192 + t4 * 2048);
      s16x8 kb1 = *(const s16x8*)(rb_hi + 8192 + t4 * 2048);
      f32x4 zz = (f32x4){0.f, 0.f, 0.f, 0.f};
      zz = __builtin_amdgcn_mfma_f32_16x16x32_bf16(kb0, qf0, zz, 0, 0, 0);
      zz = __builtin_amdgcn_mfma_f32_16x16x32_bf16(kb1, qf1, zz, 0, 0, 0);
      z1[t4] = zz;
    }
    __builtin_amdgcn_s_setprio(0);

    {
      const unsigned mlo = (unsigned)(msk0 >> lg);
      const unsigned mhi = (unsigned)(msk0 >> (lg + 32));
      float x[4][4];
#pragma unroll
      for (int t4 = 0; t4 < 4; ++t4)
#pragma unroll
        for (int r = 0; r < 4; ++r) {
          const unsigned bit = (r < 2) ? ((mlo >> (16 * r + 4 * t4)) & 1u)
                                       : ((mhi >> (16 * (r - 2) + 4 * t4)) & 1u);
          x[t4][r] = exp2f(bit ? z0[t4][r] : -1.0e9f);
        }
#pragma unroll
      for (int t4 = 0; t4 < 4; ++t4) {
        uint2 pk;
        pk.x = cvt_pk2(x[t4][0], x[t4][1]);
        pk.y = cvt_pk2(x[t4][2], x[t4][3]);
        *(uint2*)(plb + (pw0 ^ (t4 * 32))) = pk;
      }
    }
    s16x8 p00 = *(const s16x8*)(plb + pa_lo);
    s16x8 p01 = *(const s16x8*)(plb + pa_hi);

    {
      const unsigned mlo = (unsigned)(msk1 >> lg);
      const unsigned mhi = (unsigned)(msk1 >> (lg + 32));
      float x[4][4];
#pragma unroll
      for (int t4 = 0; t4 < 4; ++t4)
#pragma unroll
        for (int r = 0; r < 4; ++r) {
          const unsigned bit = (r < 2) ? ((mlo >> (16 * r + 4 * t4)) & 1u)
                                       : ((mhi >> (16 * (r - 2) + 4 * t4)) & 1u);
          x[t4][r] = exp2f(bit ? z1[t4][r] : -1.0e9f);
        }
#pragma unroll
      for (int t4 = 0; t4 < 4; ++t4) {
        uint2 pk;
        pk.x = cvt_pk2(x[t4][0], x[t4][1]);
        pk.y = cvt_pk2(x[t4][2], x[t4][3]);
        *(uint2*)(plb + (pw0 ^ (t4 * 32))) = pk;   // after pa0 reads (in-order)
      }
    }
    s16x8 p10 = *(const s16x8*)(plb + pa_lo);
    s16x8 p11 = *(const s16x8*)(plb + pa_hi);

    __builtin_amdgcn_s_setprio(1);
    f32x4 zl0 = (f32x4){0.f, 0.f, 0.f, 0.f};
    zl0 = __builtin_amdgcn_mfma_f32_16x16x32_bf16(onesf, p00, zl0, 0, 0, 0);
    zl0 = __builtin_amdgcn_mfma_f32_16x16x32_bf16(onesf, p01, zl0, 0, 0, 0);
#pragma unroll
    for (int dt = 0; dt < 4; ++dt) {
      s16x8 va0 = *(const s16x8*)(rb_lo + 16384 + dt * 2048);
      s16x8 va1 = *(const s16x8*)(rb_hi + 16384 + dt * 2048);
      out[dt] = __builtin_amdgcn_mfma_f32_16x16x32_bf16(va0, p00, out[dt], 0, 0, 0);
      out[dt] = __builtin_amdgcn_mfma_f32_16x16x32_bf16(va1, p01, out[dt], 0, 0, 0);
    }
    f32x4 zl1 = (f32x4){0.f, 0.f, 0.f, 0.f};
    zl1 = __builtin_amdgcn_mfma_f32_16x16x32_bf16(onesf, p10, zl1, 0, 0, 0);
    zl1 = __builtin_amdgcn_mfma_f32_16x16x32_bf16(onesf, p11, zl1, 0, 0, 0);
#pragma unroll
    for (int dt = 0; dt < 4; ++dt) {
      s16x8 va0 = *(const s16x8*)(rb_lo + 24576 + dt * 2048);
      s16x8 va1 = *(const s16x8*)(rb_hi + 24576 + dt * 2048);
      out[dt] = __builtin_amdgcn_mfma_f32_16x16x32_bf16(va0, p10, out[dt], 0, 0, 0);
      out[dt] = __builtin_amdgcn_mfma_f32_16x16x32_bf16(va1, p11, out[dt], 0, 0, 0);
    }
    __builtin_amdgcn_s_setprio(0);
    l_s += zl0[0] + zl1[0];

    if (more) {
      char* wb = kvb + ((cur ^ 1) << 15);
      *(uint4*)(wb + wr_k) = rk0;
      *(uint4*)(wb + (wr_k ^ 16)) = rk1;
      *(uint4*)(wb + wr_v) = rv0;
      *(uint4*)(wb + (wr_v ^ 16)) = rv1;
      msk0 = mskn0; msk1 = mskn1;
    }
    __syncthreads();
  }

  const int rowi = ((b * S_ + qr + l15) * H_) + h;
  float* pobase = po + ((size_t)half * ROWS + rowi) * 64;
#pragma unroll
  for (int dt = 0; dt < 4; ++dt) {
    float4 o = make_float4(out[dt][0], out[dt][1], out[dt][2], out[dt][3]);
    *(float4*)&pobase[dt * 16 + lg * 4] = o;
  }
  if (lg == 0) pl[(size_t)half * ROWS + rowi] = l_s;
}

// ---------------------------------------------------------------------------
extern "C" void kernel_launch(void* const* d_in, const int* in_sizes, int n_in,
                              void* d_out, int out_size, void* d_ws,
                              size_t ws_size, hipStream_t stream)
{
  const float* q_in = (const float*)d_in[0];
  const float* k_in = (const float*)d_in[1];
  const float* v_in = (const float*)d_in[2];
  const int*   mask = (const int*)d_in[3];
  const float* W1 = (const float*)d_in[4];
  const float* b1 = (const float*)d_in[5];
  const float* W2 = (const float*)d_in[6];
  const float* b2 = (const float*)d_in[7];
  const float* W3 = (const float*)d_in[8];
  const float* b3 = (const float*)d_in[9];
  const float* Wo = (const float*)d_in[10];
  const float* bo = (const float*)d_in[11];
  float* out = (float*)d_out;

  char* ws = (char*)d_ws;
  u16* qp = (u16*)ws;
  u16* kp = (u16*)(ws + (4u << 20));
  u16* vtp = (u16*)(ws + (8u << 20));
  u64* mbits = (u64*)(ws + (12u << 20));
  float* pl = (float*)(ws + (13u << 20));
  float* po = (float*)(ws + (13u << 20) + (512u << 10));

  gemm_qkv<<<dim3(M_ / 64, D_ / 128, 3), dim3(256), 0, stream>>>(
      q_in, W1, b1, qp, k_in, W2, b2, kp, v_in, W3, b3, vtp, mask, mbits);
  attn_mfma<<<dim3(S_ / 128, H_, B_ * NSPLIT), dim3(512), 0, stream>>>(
      qp, kp, vtp, mbits, po, pl);
  gemm_oproj<<<dim3(M_ / 64, D_ / 64), dim3(256), 0, stream>>>(po, pl, Wo, bo, out);
}